// Round 12
// baseline (2696.030 us; speedup 1.0000x reference)
//
#include <hip/hip_runtime.h>
#include <math.h>

// Problem constants
#define B   16
#define N   128
#define E   4
#define H   64
#define M   64
#define IN_ 32
#define T   32

typedef _Float16 f16;
typedef f16  f16x8 __attribute__((ext_vector_type(8)));
typedef float f32x4 __attribute__((ext_vector_type(4)));

#define MFMA16(a, b, c) __builtin_amdgcn_mfma_f32_16x16x32_f16(a, b, c, 0, 0, 0)

// fp16 weight pack offsets (halves)
#define OFF_W1T   0
#define OFF_W2T   32768
#define OFF_WE3H  65536
#define OFF_RI0   589824
#define OFF_RI1   602112
#define OFF_RI2   634880
#define OFF_RI3   667648
#define OFF_RJ0   671744
#define OFF_RJ1   679936
#define OFF_RJ2   712704
#define OFF_RJ3   745472
#define WPACK_SZ  749568

// Union for mega0/pg_bias: max 52224 B -> 3 blocks/CU (156672 <= 160K LDS)
union SmemU {
    struct { float xl[64][4]; f16 y1[64][136]; f16 y2[64][264]; } e;  // 52224
    struct { f16 Al[64][72]; f16 Bl[128][72]; f16 Ol[64][136]; } pg;  // 45056
    struct { float prt[4][64]; float hsum[64]; float bias[64]; } bi;  // 1536
};

// -------------------------------------------------------------------------
// prep: pad h (fp32/fp16 + hin16) AND build fp16 weight pack.
__global__ __launch_bounds__(256) void prep_kernel(
    const float* __restrict__ h_in,
    const float* __restrict__ We1, const float* __restrict__ We2,
    const float* __restrict__ We3,
    const float* __restrict__ Wi0, const float* __restrict__ Wi1,
    const float* __restrict__ Wi2, const float* __restrict__ Wi3,
    const float* __restrict__ Wj0, const float* __restrict__ Wj1,
    const float* __restrict__ Wj2, const float* __restrict__ Wj3,
    float* __restrict__ h, f16* __restrict__ h16, f16* __restrict__ hin16,
    f16* __restrict__ wp) {
    int idx = blockIdx.x * 256 + threadIdx.x;
    if (idx < B * N * H) {
        int i  = idx & (H - 1);
        int bn = idx >> 6;
        float v = (i < IN_) ? h_in[bn * IN_ + i] : 0.f;
        h[idx] = v;
        h16[idx] = (f16)v;
        if (i < IN_) hin16[bn * IN_ + i] = (f16)v;
    }
    if (idx >= WPACK_SZ) return;
    if (idx < OFF_W2T) {
        int j = idx >> 7, k = idx & 127;
        wp[idx] = (f16)We1[k * 256 + j];
    } else if (idx < OFF_WE3H) {
        int t = idx - OFF_W2T;
        int j = t >> 8, k = t & 255;
        wp[idx] = (f16)We2[k * 128 + j];
    } else if (idx < OFF_RI0) {
        wp[idx] = (f16)We3[idx - OFF_WE3H];
    } else if (idx < OFF_RI1) {
        int t = idx - OFF_RI0;
        int n = t / 96, c = t % 96;
        wp[idx] = (f16)Wi0[c * 128 + n];
    } else if (idx < OFF_RI2) {
        int t = idx - OFF_RI1;
        int n = t >> 7, k = t & 127;
        wp[idx] = (f16)Wi1[k * 256 + n];
    } else if (idx < OFF_RI3) {
        int t = idx - OFF_RI2;
        int n = t >> 8, k = t & 255;
        wp[idx] = (f16)Wi2[k * 128 + n];
    } else if (idx < OFF_RJ0) {
        int t = idx - OFF_RI3;
        int n = t >> 7, k = t & 127;
        wp[idx] = (f16)Wi3[k * 32 + n];
    } else if (idx < OFF_RJ1) {
        int t = idx - OFF_RJ0;
        int n = t >> 6, c = t & 63;
        wp[idx] = (f16)Wj0[c * 128 + n];
    } else if (idx < OFF_RJ2) {
        int t = idx - OFF_RJ1;
        int n = t >> 7, k = t & 127;
        wp[idx] = (f16)Wj1[k * 256 + n];
    } else if (idx < OFF_RJ3) {
        int t = idx - OFF_RJ2;
        int n = t >> 8, k = t & 255;
        wp[idx] = (f16)Wj2[k * 128 + n];
    } else {
        int t = idx - OFF_RJ3;
        int n = t >> 7, k = t & 127;
        wp[idx] = (f16)Wj3[k * 32 + n];
    }
}

// ===================== task bodies ========================================

__device__ void edge_body(SmemU& su, int tid, int tile,
                          const float* __restrict__ am,
                          const float* __restrict__ We0,
                          const float* __restrict__ be0,
                          const f16* __restrict__ W1t,
                          const float* __restrict__ be1,
                          const f16* __restrict__ W2t,
                          const float* __restrict__ be2,
                          f16* __restrict__ f) {
    int lane = tid & 63, wv = tid >> 6;
    long long g0 = (long long)tile * 64;

    ((float*)su.e.xl)[tid] = am[g0 * 4 + tid];
    __syncthreads();

    {   // layer 1: K=4, VALU
        int j = tid & 127, e0 = (tid >> 7) * 32;
        float w0 = We0[j], w1 = We0[128 + j], w2 = We0[256 + j], w3 = We0[384 + j];
        float bb = be0[j];
        #pragma unroll 8
        for (int e = e0; e < e0 + 32; ++e) {
            float v = bb + su.e.xl[e][0] * w0 + su.e.xl[e][1] * w1
                         + su.e.xl[e][2] * w2 + su.e.xl[e][3] * w3;
            su.e.y1[e][j] = (f16)fmaxf(v, 0.f);
        }
    }
    __syncthreads();

    int m = lane & 15, q = lane >> 4;

    {   // layer 2
        f32x4 acc[4][4];
        #pragma unroll
        for (int ct = 0; ct < 4; ++ct)
            #pragma unroll
            for (int rt = 0; rt < 4; ++rt) acc[ct][rt] = (f32x4){0.f, 0.f, 0.f, 0.f};
        #pragma unroll
        for (int s = 0; s < 4; ++s) {
            int k0 = s * 32 + q * 8;
            f16x8 afr[4], bfr[4];
            #pragma unroll
            for (int rt = 0; rt < 4; ++rt)
                afr[rt] = *(const f16x8*)&su.e.y1[rt * 16 + m][k0];
            #pragma unroll
            for (int ct = 0; ct < 4; ++ct) {
                int n = (wv * 4 + ct) * 16 + m;
                bfr[ct] = *(const f16x8*)(W1t + n * 128 + k0);
            }
            #pragma unroll
            for (int ct = 0; ct < 4; ++ct)
                #pragma unroll
                for (int rt = 0; rt < 4; ++rt)
                    acc[ct][rt] = MFMA16(afr[rt], bfr[ct], acc[ct][rt]);
        }
        #pragma unroll
        for (int ct = 0; ct < 4; ++ct) {
            int n = (wv * 4 + ct) * 16 + m;
            float bb = be1[n];
            #pragma unroll
            for (int rt = 0; rt < 4; ++rt)
                #pragma unroll
                for (int r = 0; r < 4; ++r) {
                    int row = rt * 16 + q * 4 + r;
                    su.e.y2[row][n] = (f16)fmaxf(acc[ct][rt][r] + bb, 0.f);
                }
        }
    }
    __syncthreads();

    {   // layer 3 (out-stage back into y1)
        f32x4 acc[2][4];
        #pragma unroll
        for (int ct = 0; ct < 2; ++ct)
            #pragma unroll
            for (int rt = 0; rt < 4; ++rt) acc[ct][rt] = (f32x4){0.f, 0.f, 0.f, 0.f};
        #pragma unroll
        for (int s = 0; s < 8; ++s) {
            int k0 = s * 32 + q * 8;
            f16x8 afr[4], bfr[2];
            #pragma unroll
            for (int rt = 0; rt < 4; ++rt)
                afr[rt] = *(const f16x8*)&su.e.y2[rt * 16 + m][k0];
            #pragma unroll
            for (int ct = 0; ct < 2; ++ct) {
                int n = (wv * 2 + ct) * 16 + m;
                bfr[ct] = *(const f16x8*)(W2t + n * 256 + k0);
            }
            #pragma unroll
            for (int ct = 0; ct < 2; ++ct)
                #pragma unroll
                for (int rt = 0; rt < 4; ++rt)
                    acc[ct][rt] = MFMA16(afr[rt], bfr[ct], acc[ct][rt]);
        }
        #pragma unroll
        for (int ct = 0; ct < 2; ++ct) {
            int n = (wv * 2 + ct) * 16 + m;
            float bb = be2[n];
            #pragma unroll
            for (int rt = 0; rt < 4; ++rt)
                #pragma unroll
                for (int r = 0; r < 4; ++r) {
                    int row = rt * 16 + q * 4 + r;
                    su.e.y1[row][n] = (f16)fmaxf(acc[ct][rt][r] + bb, 0.f);
                }
        }
    }
    __syncthreads();

    #pragma unroll
    for (int j = 0; j < 4; ++j) {
        int c = tid + j * 256;
        int e = c >> 4, pp = c & 15;
        *(uint4*)(f + (g0 + e) * 128 + pp * 8) = *(const uint4*)&su.e.y1[e][pp * 8];
    }
}

// 64-node-row P tile: P2[(b,w),o,k], rows nt*64..+63
__device__ void pgemm_body(SmemU& su, int tid, int ob, int nt,
                           const f16* __restrict__ h16,
                           const f16* __restrict__ We3h,
                           f16* __restrict__ P2) {
    int lane = tid & 63, wv = tid >> 6;

    #pragma unroll
    for (int j = 0; j < 2; ++j) {
        int c = tid + j * 256;        // 0..511 : 64 rows x 8 uint4
        int row = c >> 3, pp = c & 7;
        *(uint4*)&su.pg.Al[row][pp * 8] =
            *(const uint4*)(h16 + (size_t)(nt * 64 + row) * 64 + pp * 8);
    }
    #pragma unroll
    for (int j = 0; j < 4; ++j) {
        int c = tid + j * 256;        // 0..1023 : 128 k-rows x 8 uint4
        int k = c >> 3, pp = c & 7;
        *(uint4*)&su.pg.Bl[k][pp * 8] =
            *(const uint4*)(We3h + ((size_t)(k * 64 + ob)) * 64 + pp * 8);
    }
    __syncthreads();

    int m = lane & 15, q = lane >> 4;
    f32x4 acc[2][4];
    #pragma unroll
    for (int ct = 0; ct < 2; ++ct)
        #pragma unroll
        for (int rt = 0; rt < 4; ++rt) acc[ct][rt] = (f32x4){0.f, 0.f, 0.f, 0.f};
    #pragma unroll
    for (int s = 0; s < 2; ++s) {
        int k0 = s * 32 + q * 8;
        f16x8 afr[4], bfr[2];
        #pragma unroll
        for (int rt = 0; rt < 4; ++rt)
            afr[rt] = *(const f16x8*)&su.pg.Al[rt * 16 + m][k0];
        #pragma unroll
        for (int ct = 0; ct < 2; ++ct)
            bfr[ct] = *(const f16x8*)&su.pg.Bl[(wv * 2 + ct) * 16 + m][k0];
        #pragma unroll
        for (int ct = 0; ct < 2; ++ct)
            #pragma unroll
            for (int rt = 0; rt < 4; ++rt)
                acc[ct][rt] = MFMA16(afr[rt], bfr[ct], acc[ct][rt]);
    }
    #pragma unroll
    for (int ct = 0; ct < 2; ++ct) {
        int col = (wv * 2 + ct) * 16 + m;
        #pragma unroll
        for (int rt = 0; rt < 4; ++rt)
            #pragma unroll
            for (int r = 0; r < 4; ++r)
                su.pg.Ol[rt * 16 + q * 4 + r][col] = (f16)acc[ct][rt][r];
    }
    __syncthreads();
    #pragma unroll
    for (int j = 0; j < 4; ++j) {
        int c = tid + j * 256;        // 0..1023 : 64 rows x 16 uint4
        int row = c >> 4, pp = c & 15;
        *(uint4*)(P2 + ((size_t)(nt * 64 + row) * 64 + ob) * 128 + pp * 8) =
            *(const uint4*)&su.pg.Ol[row][pp * 8];
    }
}

// bias: msg[b,v,o] = bias[b,o] (full accumulator init, R10-proven)
__device__ void bias_body(SmemU& su, int tid, int b,
                          const float* __restrict__ h,
                          const float* __restrict__ be3,
                          float* __restrict__ msg) {
    int i = tid & 63, wq = tid >> 6;
    float s = 0.f;
    for (int w = wq; w < N; w += 4) s += h[((size_t)(b * N + w)) * H + i];
    su.bi.prt[wq][i] = s;
    __syncthreads();
    if (tid < 64)
        su.bi.hsum[tid] = su.bi.prt[0][tid] + su.bi.prt[1][tid]
                        + su.bi.prt[2][tid] + su.bi.prt[3][tid];
    __syncthreads();
    if (tid < 64) {
        float sb = 0.f;
        #pragma unroll 4
        for (int ii = 0; ii < H; ++ii) sb += be3[tid * H + ii] * su.bi.hsum[ii];
        su.bi.bias[tid] = sb;
    }
    __syncthreads();
    for (int idx = tid; idx < N * M; idx += 256)
        msg[(size_t)b * N * M + idx] = su.bi.bias[idx & 63];
}

// -------------------------------------------------------------------------
// mega0: edge (0..4095) + L0 pgemm64 (4096..6143) + L0 bias (6144..6159)
__global__ __launch_bounds__(256, 3) void mega0_kernel(
    const float* __restrict__ am,
    const float* __restrict__ We0, const float* __restrict__ be0,
    const float* __restrict__ be1, const float* __restrict__ be2,
    const float* __restrict__ be3,
    const f16* __restrict__ wp,
    const float* __restrict__ h, const f16* __restrict__ h16,
    f16* __restrict__ f, f16* __restrict__ P2, float* __restrict__ msg) {
    __shared__ SmemU su;
    int tid = threadIdx.x;
    int bid = blockIdx.x;
    if (bid < 4096) {
        edge_body(su, tid, bid, am, We0, be0, wp + OFF_W1T, be1, wp + OFF_W2T,
                  be2, f);
    } else if (bid < 6144) {
        int t = bid - 4096;
        pgemm_body(su, tid, t & 63, t >> 6, h16, wp + OFF_WE3H, P2);
    } else {
        bias_body(su, tid, bid - 6144, h, be3, msg);
    }
}

// pg_bias: pgemm64 (0..2047) + bias (2048..2063), for layers 1,2
__global__ __launch_bounds__(256, 3) void pg_bias_kernel(
    const float* __restrict__ be3, const f16* __restrict__ wp,
    const float* __restrict__ h, const f16* __restrict__ h16,
    f16* __restrict__ P2, float* __restrict__ msg) {
    __shared__ SmemU su;
    int tid = threadIdx.x;
    int bid = blockIdx.x;
    if (bid < 2048) {
        pgemm_body(su, tid, bid & 63, bid >> 6, h16, wp + OFF_WE3H, P2);
    } else {
        bias_body(su, tid, bid - 2048, h, be3, msg);
    }
}

// -------------------------------------------------------------------------
// msg_gru: split-K msg GEMM (grid 32x16, R10-proven atomic accumulate) +
// per-b last-block GRU tail. done[b] counts arrived split-blocks.
__global__ __launch_bounds__(256, 2) void msg_gru_kernel(
    const f16* __restrict__ f, const f16* __restrict__ P2,
    float* __restrict__ msg,
    float* __restrict__ h, f16* __restrict__ h16,
    const float* __restrict__ Wih, const float* __restrict__ Whh,
    const float* __restrict__ bih, const float* __restrict__ bhh,
    const int* __restrict__ g_size, int* __restrict__ done) {
    __shared__ union {
        struct { f16 Al[128][136]; f16 Bl[64][136]; } st;       // 52224
        struct { float msgl[128][64]; float hl[128][64]; } gr;  // 65536
    } su;
    __shared__ int lastflag;
    int tid = threadIdx.x, lane = tid & 63, wv = tid >> 6;
    int ws = blockIdx.x;
    int b  = blockIdx.y;
    int m = lane & 15, q = lane >> 4;

    // ---- GEMM part (R10-proven)
    f32x4 acc[2][4];
    #pragma unroll
    for (int rt = 0; rt < 2; ++rt)
        #pragma unroll
        for (int ct = 0; ct < 4; ++ct) acc[rt][ct] = (f32x4){0.f, 0.f, 0.f, 0.f};

    for (int wi = 0; wi < 4; ++wi) {
        int w = ws * 4 + wi;
        #pragma unroll
        for (int j = 0; j < 8; ++j) {
            int c = tid + j * 256;
            int v = c >> 4, pp = c & 15;
            *(uint4*)&su.st.Al[v][pp * 8] =
                *(const uint4*)(f + (((size_t)(b * 128 + v) * 128 + w) * 128) + pp * 8);
        }
        #pragma unroll
        for (int j = 0; j < 4; ++j) {
            int c = tid + j * 256;
            int o = c >> 4, pp = c & 15;
            *(uint4*)&su.st.Bl[o][pp * 8] =
                *(const uint4*)(P2 + (((size_t)(b * 128 + w) * 64 + o) * 128) + pp * 8);
        }
        __syncthreads();
        #pragma unroll
        for (int s = 0; s < 4; ++s) {
            int k0 = s * 32 + q * 8;
            f16x8 afr[2], bfr[4];
            #pragma unroll
            for (int rt = 0; rt < 2; ++rt)
                afr[rt] = *(const f16x8*)&su.st.Al[(wv * 2 + rt) * 16 + m][k0];
            #pragma unroll
            for (int ct = 0; ct < 4; ++ct)
                bfr[ct] = *(const f16x8*)&su.st.Bl[ct * 16 + m][k0];
            #pragma unroll
            for (int rt = 0; rt < 2; ++rt)
                #pragma unroll
                for (int ct = 0; ct < 4; ++ct)
                    acc[rt][ct] = MFMA16(afr[rt], bfr[ct], acc[rt][ct]);
        }
        __syncthreads();
    }
    #pragma unroll
    for (int rt = 0; rt < 2; ++rt)
        #pragma unroll
        for (int ct = 0; ct < 4; ++ct) {
            int o = ct * 16 + m;
            #pragma unroll
            for (int r = 0; r < 4; ++r) {
                int v = (wv * 2 + rt) * 16 + q * 4 + r;
                atomicAdd(msg + (size_t)(b * 128 + v) * 64 + o, acc[rt][ct][r]);
            }
        }

    // ---- tail: last split-block of this b runs the GRU for 128 nodes
    __syncthreads();
    __threadfence();                       // release: atomics ordered/visible
    if (tid == 0) lastflag = (atomicAdd(&done[b], 1) == 31);
    __syncthreads();
    if (!lastflag) return;
    __threadfence();                       // acquire: invalidate stale lines

    #pragma unroll
    for (int j = 0; j < 8; ++j) {          // stage msg (2048 float4)
        int c = tid + j * 256;
        int row = c >> 4, pp = c & 15;
        *(float4*)&su.gr.msgl[row][pp * 4] =
            *(const float4*)(msg + (size_t)(b * 128 + row) * 64 + pp * 4);
    }
    #pragma unroll
    for (int j = 0; j < 8; ++j) {          // stage h
        int c = tid + j * 256;
        int row = c >> 4, pp = c & 15;
        *(float4*)&su.gr.hl[row][pp * 4] =
            *(const float4*)(h + (size_t)(b * 128 + row) * 64 + pp * 4);
    }
    __syncthreads();

    int gs = g_size[b];
    #pragma unroll 2
    for (int j = 0; j < 32; ++j) {         // 8192 (n,i) pairs / 256 threads
        int c = tid + j * 256;
        int n = c >> 6, i = c & 63;
        float sr = bih[i], sz = bih[64 + i], sn = bih[128 + i];
        float tr = bhh[i], tz = bhh[64 + i], tn = bhh[128 + i];
        const float* wr = Wih + i * 64;
        const float* wz = Wih + (64 + i) * 64;
        const float* wn = Wih + (128 + i) * 64;
        const float* ur = Whh + i * 64;
        const float* uz = Whh + (64 + i) * 64;
        const float* un = Whh + (128 + i) * 64;
        #pragma unroll 4
        for (int k = 0; k < 64; ++k) {
            float mk = su.gr.msgl[n][k];
            float hk = su.gr.hl[n][k];
            sr += wr[k] * mk;  sz += wz[k] * mk;  sn += wn[k] * mk;
            tr += ur[k] * hk;  tz += uz[k] * hk;  tn += un[k] * hk;
        }
        float r = 1.f / (1.f + expf(-(sr + tr)));
        float z = 1.f / (1.f + expf(-(sz + tz)));
        float nn = tanhf(sn + r * tn);
        float hv = (1.f - z) * nn + z * su.gr.hl[n][i];
        float maskf = (n < gs) ? 1.f : 0.f;
        hv *= maskf;
        size_t row = (size_t)(b * 128 + n);
        h[row * 64 + i] = hv;
        h16[row * 64 + i] = (f16)hv;
    }
}

// -------------------------------------------------------------------------
// Readout via MFMA + fused finalize (last-block pattern, R11-proven).
__global__ __launch_bounds__(256, 4) void readout_final(
    const f16* __restrict__ h16, const f16* __restrict__ hin16,
    const int* __restrict__ g_size, const f16* __restrict__ wp,
    const float* __restrict__ bi0, const float* __restrict__ bi1,
    const float* __restrict__ bi2, const float* __restrict__ bi3,
    const float* __restrict__ bj0, const float* __restrict__ bj1,
    const float* __restrict__ bj2, const float* __restrict__ bj3,
    float* __restrict__ contrib, float* __restrict__ out,
    int* __restrict__ done) {
    __shared__ f16 Xl[32][104];
    __shared__ f16 A1[32][136];
    __shared__ f16 A2[32][264];
    __shared__ float Gl[32][36];
    __shared__ float fin[T];
    __shared__ int lastflag;
    const f16* Ri0 = wp + OFF_RI0; const f16* Ri1 = wp + OFF_RI1;
    const f16* Ri2 = wp + OFF_RI2; const f16* Ri3 = wp + OFF_RI3;
    const f16* Rj0 = wp + OFF_RJ0; const f16* Rj1 = wp + OFF_RJ1;
    const f16* Rj2 = wp + OFF_RJ2; const f16* Rj3 = wp + OFF_RJ3;
    int tid = threadIdx.x, lane = tid & 63, wv = tid >> 6;
    int m = lane & 15, q = lane >> 4;
    int r0 = blockIdx.x * 32;

    {
        int row = tid >> 3, pp = tid & 7;
        *(uint4*)&Xl[row][pp * 8] = *(const uint4*)(h16 + (size_t)(r0 + row) * 64 + pp * 8);
        if (tid < 128) {
            int row2 = tid >> 2, p2 = tid & 3;
            *(uint4*)&Xl[row2][64 + p2 * 8] =
                *(const uint4*)(hin16 + (size_t)(r0 + row2) * 32 + p2 * 8);
        }
    }
    __syncthreads();

    // i-chain L0
    {
        f32x4 acc[2][2];
        #pragma unroll
        for (int ct = 0; ct < 2; ++ct)
            #pragma unroll
            for (int rt = 0; rt < 2; ++rt) acc[ct][rt] = (f32x4){0.f, 0.f, 0.f, 0.f};
        #pragma unroll
        for (int s = 0; s < 3; ++s) {
            int k0 = s * 32 + q * 8;
            f16x8 afr[2], bfr[2];
            #pragma unroll
            for (int rt = 0; rt < 2; ++rt) afr[rt] = *(const f16x8*)&Xl[rt * 16 + m][k0];
            #pragma unroll
            for (int ct = 0; ct < 2; ++ct)
                bfr[ct] = *(const f16x8*)(Ri0 + ((wv * 2 + ct) * 16 + m) * 96 + k0);
            #pragma unroll
            for (int ct = 0; ct < 2; ++ct)
                #pragma unroll
                for (int rt = 0; rt < 2; ++rt)
                    acc[ct][rt] = MFMA16(afr[rt], bfr[ct], acc[ct][rt]);
        }
        #pragma unroll
        for (int ct = 0; ct < 2; ++ct) {
            int n = (wv * 2 + ct) * 16 + m;
            float bb = bi0[n];
            #pragma unroll
            for (int rt = 0; rt < 2; ++rt)
                #pragma unroll
                for (int r = 0; r < 4; ++r)
                    A1[rt * 16 + q * 4 + r][n] = (f16)fmaxf(acc[ct][rt][r] + bb, 0.f);
        }
    }
    __syncthreads();

    // i-chain L1
    {
        f32x4 acc[4][2];
        #pragma unroll
        for (int ct = 0; ct < 4; ++ct)
            #pragma unroll
            for (int rt = 0; rt < 2; ++rt) acc[ct][rt] = (f32x4){0.f, 0.f, 0.f, 0.f};
        #pragma unroll
        for (int s = 0; s < 4; ++s) {
            int k0 = s * 32 + q * 8;
            f16x8 afr[2], bfr[4];
            #pragma unroll
            for (int rt = 0; rt < 2; ++rt) afr[rt] = *(const f16x8*)&A1[rt * 16 + m][k0];
            #pragma unroll
            for (int ct = 0; ct < 4; ++ct)
                bfr[ct] = *(const f16x8*)(Ri1 + ((wv * 4 + ct) * 16 + m) * 128 + k0);
            #pragma unroll
            for (int ct = 0; ct < 4; ++ct)
                #pragma unroll
                for (int rt = 0; rt < 2; ++rt)
                    acc[ct][rt] = MFMA16(afr[rt], bfr[ct], acc[ct][rt]);
        }
        #pragma unroll
        for (int ct = 0; ct < 4; ++ct) {
            int n = (wv * 4 + ct) * 16 + m;
            float bb = bi1[n];
            #pragma unroll
            for (int rt = 0; rt < 2; ++rt)
                #pragma unroll
                for (int r = 0; r < 4; ++r)
                    A2[rt * 16 + q * 4 + r][n] = (f16)fmaxf(acc[ct][rt][r] + bb, 0.f);
        }
    }
    __syncthreads();

    // i-chain L2
    {
        f32x4 acc[2][2];
        #pragma unroll
        for (int ct = 0; ct < 2; ++ct)
            #pragma unroll
            for (int rt = 0; rt < 2; ++rt) acc[ct][rt] = (f32x4){0.f, 0.f, 0.f, 0.f};
        #pragma unroll
        for (int s = 0; s < 8; ++s) {
            int k0 = s * 32 + q * 8;
            f16x8 afr[2], bfr[2];
            #pragma unroll
            for (int rt = 0; rt < 2; ++rt) afr[rt] = *(const f16x8*)&A2[rt * 16 + m][k0];
            #pragma unroll
            for (int ct = 0; ct < 2; ++ct)
                bfr[ct] = *(const f16x8*)(Ri2 + ((wv * 2 + ct) * 16 + m) * 256 + k0);
            #pragma unroll
            for (int ct = 0; ct < 2; ++ct)
                #pragma unroll
                for (int rt = 0; rt < 2; ++rt)
                    acc[ct][rt] = MFMA16(afr[rt], bfr[ct], acc[ct][rt]);
        }
        __syncthreads();
        #pragma unroll
        for (int ct = 0; ct < 2; ++ct) {
            int n = (wv * 2 + ct) * 16 + m;
            float bb = bi2[n];
            #pragma unroll
            for (int rt = 0; rt < 2; ++rt)
                #pragma unroll
                for (int r = 0; r < 4; ++r)
                    A1[rt * 16 + q * 4 + r][n] = (f16)fmaxf(acc[ct][rt][r] + bb, 0.f);
        }
    }
    __syncthreads();

    // i-chain L3 -> gate
    if (wv < 2) {
        f32x4 acc[2];
        acc[0] = (f32x4){0.f, 0.f, 0.f, 0.f};
        acc[1] = (f32x4){0.f, 0.f, 0.f, 0.f};
        int n = wv * 16 + m;
        #pragma unroll
        for (int s = 0; s < 4; ++s) {
            int k0 = s * 32 + q * 8;
            f16x8 bfr = *(const f16x8*)(Ri3 + n * 128 + k0);
            #pragma unroll
            for (int rt = 0; rt < 2; ++rt) {
                f16x8 afr = *(const f16x8*)&A1[rt * 16 + m][k0];
                acc[rt] = MFMA16(afr, bfr, acc[rt]);
            }
        }
        float bb = bi3[n];
        #pragma unroll
        for (int rt = 0; rt < 2; ++rt)
            #pragma unroll
            for (int r = 0; r < 4; ++r)
                Gl[rt * 16 + q * 4 + r][n] = 1.f / (1.f + expf(-(acc[rt][r] + bb)));
    }
    __syncthreads();

    // j-chain L0
    {
        f32x4 acc[2][2];
        #pragma unroll
        for (int ct = 0; ct < 2; ++ct)
            #pragma unroll
            for (int rt = 0; rt < 2; ++rt) acc[ct][rt] = (f32x4){0.f, 0.f, 0.f, 0.f};
        #pragma unroll
        for (int s = 0; s < 2; ++s) {
            int k0 = s * 32 + q * 8;
            f16x8 afr[2], bfr[2];
            #pragma unroll
            for (int rt = 0; rt < 2; ++rt) afr[rt] = *(const f16x8*)&Xl[rt * 16 + m][k0];
            #pragma unroll
            for (int ct = 0; ct < 2; ++ct)
                bfr[ct] = *(const f16x8*)(Rj0 + ((wv * 2 + ct) * 16 + m) * 64 + k0);
            #pragma unroll
            for (int ct = 0; ct < 2; ++ct)
                #pragma unroll
                for (int rt = 0; rt < 2; ++rt)
                    acc[ct][rt] = MFMA16(afr[rt], bfr[ct], acc[ct][rt]);
        }
        __syncthreads();
        #pragma unroll
        for (int ct = 0; ct < 2; ++ct) {
            int n = (wv * 2 + ct) * 16 + m;
            float bb = bj0[n];
            #pragma unroll
            for (int rt = 0; rt < 2; ++rt)
                #pragma unroll
                for (int r = 0; r < 4; ++r)
                    A1[rt * 16 + q * 4 + r][n] = (f16)fmaxf(acc[ct][rt][r] + bb, 0.f);
        }
    }
    __syncthreads();

    // j-chain L1
    {
        f32x4 acc[4][2];
        #pragma unroll
        for (int ct = 0; ct < 4; ++ct)
            #pragma unroll
            for (int rt = 0; rt < 2; ++rt) acc[ct][rt] = (f32x4){0.f, 0.f, 0.f, 0.f};
        #pragma unroll
        for (int s = 0; s < 4; ++s) {
            int k0 = s * 32 + q * 8;
            f16x8 afr[2], bfr[4];
            #pragma unroll
            for (int rt = 0; rt < 2; ++rt) afr[rt] = *(const f16x8*)&A1[rt * 16 + m][k0];
            #pragma unroll
            for (int ct = 0; ct < 4; ++ct)
                bfr[ct] = *(const f16x8*)(Rj1 + ((wv * 4 + ct) * 16 + m) * 128 + k0);
            #pragma unroll
            for (int ct = 0; ct < 4; ++ct)
                #pragma unroll
                for (int rt = 0; rt < 2; ++rt)
                    acc[ct][rt] = MFMA16(afr[rt], bfr[ct], acc[ct][rt]);
        }
        #pragma unroll
        for (int ct = 0; ct < 4; ++ct) {
            int n = (wv * 4 + ct) * 16 + m;
            float bb = bj1[n];
            #pragma unroll
            for (int rt = 0; rt < 2; ++rt)
                #pragma unroll
                for (int r = 0; r < 4; ++r)
                    A2[rt * 16 + q * 4 + r][n] = (f16)fmaxf(acc[ct][rt][r] + bb, 0.f);
        }
    }
    __syncthreads();

    // j-chain L2
    {
        f32x4 acc[2][2];
        #pragma unroll
        for (int ct = 0; ct < 2; ++ct)
            #pragma unroll
            for (int rt = 0; rt < 2; ++rt) acc[ct][rt] = (f32x4){0.f, 0.f, 0.f, 0.f};
        #pragma unroll
        for (int s = 0; s < 8; ++s) {
            int k0 = s * 32 + q * 8;
            f16x8 afr[2], bfr[2];
            #pragma unroll
            for (int rt = 0; rt < 2; ++rt) afr[rt] = *(const f16x8*)&A2[rt * 16 + m][k0];
            #pragma unroll
            for (int ct = 0; ct < 2; ++ct)
                bfr[ct] = *(const f16x8*)(Rj2 + ((wv * 2 + ct) * 16 + m) * 256 + k0);
            #pragma unroll
            for (int ct = 0; ct < 2; ++ct)
                #pragma unroll
                for (int rt = 0; rt < 2; ++rt)
                    acc[ct][rt] = MFMA16(afr[rt], bfr[ct], acc[ct][rt]);
        }
        __syncthreads();
        #pragma unroll
        for (int ct = 0; ct < 2; ++ct) {
            int n = (wv * 2 + ct) * 16 + m;
            float bb = bj2[n];
            #pragma unroll
            for (int rt = 0; rt < 2; ++rt)
                #pragma unroll
                for (int r = 0; r < 4; ++r)
                    A1[rt * 16 + q * 4 + r][n] = (f16)fmaxf(acc[ct][rt][r] + bb, 0.f);
        }
    }
    __syncthreads();

    // j-chain L3 + combine
    if (wv < 2) {
        f32x4 acc[2];
        acc[0] = (f32x4){0.f, 0.f, 0.f, 0.f};
        acc[1] = (f32x4){0.f, 0.f, 0.f, 0.f};
        int n = wv * 16 + m;
        #pragma unroll
        for (int s = 0; s < 4; ++s) {
            int k0 = s * 32 + q * 8;
            f16x8 bfr = *(const f16x8*)(Rj3 + n * 128 + k0);
            #pragma unroll
            for (int rt = 0; rt < 2; ++rt) {
                f16x8 afr = *(const f16x8*)&A1[rt * 16 + m][k0];
                acc[rt] = MFMA16(afr, bfr, acc[rt]);
            }
        }
        float bb = bj3[n];
        #pragma unroll
        for (int rt = 0; rt < 2; ++rt)
            #pragma unroll
            for (int r = 0; r < 4; ++r) {
                int row = rt * 16 + q * 4 + r;
                int rg = r0 + row;
                int bb2 = rg >> 7, v = rg & 127;
                float maskf = (v < g_size[bb2]) ? 1.f : 0.f;
                contrib[(size_t)rg * T + n] = maskf * Gl[row][n] * (acc[rt][r] + bb);
            }
    }

    // ---- fused finalize: last arriving block does the 16 log_softmax rows
    __syncthreads();
    __threadfence();
    if (tid == 0) lastflag = (atomicAdd(done, 1) == 63);
    __syncthreads();
    if (!lastflag) return;
    __threadfence();
    for (int b = 0; b < B; ++b) {
        if (tid < T) {
            float s = 0.f;
            for (int v = 0; v < N; ++v) s += contrib[(b * N + v) * T + tid];
            fin[tid] = s;
        }
        __syncthreads();
        if (tid < T) {
            float mx = fin[0];
            for (int i = 1; i < T; ++i) mx = fmaxf(mx, fin[i]);
            float se = 0.f;
            for (int i = 0; i < T; ++i) se += expf(fin[i] - mx);
            out[b * T + tid] = fin[tid] - mx - logf(se);
        }
        __syncthreads();
    }
}

// -------------------------------------------------------------------------
extern "C" void kernel_launch(void* const* d_in, const int* in_sizes, int n_in,
                              void* d_out, int out_size, void* d_ws, size_t ws_size,
                              hipStream_t stream) {
    (void)in_sizes; (void)n_in; (void)out_size; (void)ws_size;
    const float* h_in = (const float*)d_in[0];
    const float* am   = (const float*)d_in[1];
    const int*   g_sz = (const int*)d_in[2];
    const float* We0 = (const float*)d_in[3],  *be0 = (const float*)d_in[4];
    const float* We1 = (const float*)d_in[5],  *be1 = (const float*)d_in[6];
    const float* We2 = (const float*)d_in[7],  *be2 = (const float*)d_in[8];
    const float* We3 = (const float*)d_in[9],  *be3 = (const float*)d_in[10];
    const float* Wih = (const float*)d_in[11], *Whh = (const float*)d_in[12];
    const float* bih = (const float*)d_in[13], *bhh = (const float*)d_in[14];
    const float* Wi0 = (const float*)d_in[15], *bi0 = (const float*)d_in[16];
    const float* Wj0 = (const float*)d_in[17], *bj0 = (const float*)d_in[18];
    const float* Wi1 = (const float*)d_in[19], *bi1 = (const float*)d_in[20];
    const float* Wj1 = (const float*)d_in[21], *bj1 = (const float*)d_in[22];
    const float* Wi2 = (const float*)d_in[23], *bi2 = (const float*)d_in[24];
    const float* Wj2 = (const float*)d_in[25], *bj2 = (const float*)d_in[26];
    const float* Wi3 = (const float*)d_in[27], *bi3 = (const float*)d_in[28];
    const float* Wj3 = (const float*)d_in[29], *bj3 = (const float*)d_in[30];

    float* out = (float*)d_out;

    // workspace layout: counters first (memset target): done_msg[3*16], done_ro
    int*   done_msg = (int*)d_ws;                          // 48 ints
    int*   done_ro  = (int*)d_ws + 64;                     // 1 int
    f16*   f    = (f16*)((char*)d_ws + 1024);              // 33554432 halves
    f16*   P2   = f + (size_t)33554432;                    // 16777216 halves
    float* msg  = (float*)(P2 + (size_t)16777216);         // 131072 floats
    float* h    = msg + 131072;                            // 131072
    float* contrib = h + 131072;                           // 65536
    f16*   h16  = (f16*)(contrib + 65536);                 // 131072 halves
    f16*   hin16 = h16 + 131072;                           // 65536 halves
    f16*   wp   = hin16 + 65536;                           // 749568 halves

    hipMemsetAsync(d_ws, 0, 1024, stream);
    prep_kernel<<<(WPACK_SZ + 255) / 256, 256, 0, stream>>>(
        h_in, We1, We2, We3, Wi0, Wi1, Wi2, Wi3, Wj0, Wj1, Wj2, Wj3,
        h, h16, hin16, wp);

    // layer 0: edge + pgemm64 + bias-init(msg) in one launch
    mega0_kernel<<<4096 + 2048 + 16, 256, 0, stream>>>(
        am, We0, be0, be1, be2, be3, wp, h, h16, f, P2, msg);
    msg_gru_kernel<<<dim3(32, 16), 256, 0, stream>>>(f, P2, msg, h, h16,
                                                     Wih, Whh, bih, bhh, g_sz,
                                                     done_msg + 0);

    for (int l = 1; l < 3; ++l) {
        pg_bias_kernel<<<2048 + 16, 256, 0, stream>>>(be3, wp, h, h16, P2, msg);
        msg_gru_kernel<<<dim3(32, 16), 256, 0, stream>>>(f, P2, msg, h, h16,
                                                         Wih, Whh, bih, bhh, g_sz,
                                                         done_msg + l * 16);
    }

    readout_final<<<64, 256, 0, stream>>>(h16, hin16, g_sz, wp,
                                          bi0, bi1, bi2, bi3,
                                          bj0, bj1, bj2, bj3, contrib, out,
                                          done_ro);
}

// Round 13
// 463.652 us; speedup vs baseline: 5.8148x; 5.8148x over previous
//
#include <hip/hip_runtime.h>
#include <math.h>

// Problem constants
#define B   16
#define N   128
#define E   4
#define H   64
#define M   64
#define IN_ 32
#define T   32

typedef _Float16 f16;
typedef f16  f16x8 __attribute__((ext_vector_type(8)));
typedef float f32x4 __attribute__((ext_vector_type(4)));

#define MFMA16(a, b, c) __builtin_amdgcn_mfma_f32_16x16x32_f16(a, b, c, 0, 0, 0)

// fp16 weight pack offsets (halves)
#define OFF_W1T   0
#define OFF_W2T   32768
#define OFF_WE3H  65536
#define OFF_RI0   589824
#define OFF_RI1   602112
#define OFF_RI2   634880
#define OFF_RI3   667648
#define OFF_RJ0   671744
#define OFF_RJ1   679936
#define OFF_RJ2   712704
#define OFF_RJ3   745472
#define WPACK_SZ  749568

// Union for mega0/pg_bias: max 52224 B -> 3 blocks/CU (156672 <= 160K LDS)
union SmemU {
    struct { float xl[64][4]; f16 y1[64][136]; f16 y2[64][264]; } e;  // 52224
    struct { f16 Al[64][72]; f16 Bl[128][72]; f16 Ol[64][136]; } pg;  // 45056
    struct { float prt[4][64]; float hsum[64]; } bi;                  // 1280
};

// -------------------------------------------------------------------------
// prep: pad h, build fp16 weight pack, zero done counters (no memset launch).
__global__ __launch_bounds__(256) void prep_kernel(
    const float* __restrict__ h_in,
    const float* __restrict__ We1, const float* __restrict__ We2,
    const float* __restrict__ We3,
    const float* __restrict__ Wi0, const float* __restrict__ Wi1,
    const float* __restrict__ Wi2, const float* __restrict__ Wi3,
    const float* __restrict__ Wj0, const float* __restrict__ Wj1,
    const float* __restrict__ Wj2, const float* __restrict__ Wj3,
    float* __restrict__ h, f16* __restrict__ h16, f16* __restrict__ hin16,
    f16* __restrict__ wp, int* __restrict__ done) {
    int idx = blockIdx.x * 256 + threadIdx.x;
    if (blockIdx.x == 0 && threadIdx.x < 64) done[threadIdx.x] = 0;
    if (idx < B * N * H) {
        int i  = idx & (H - 1);
        int bn = idx >> 6;
        float v = (i < IN_) ? h_in[bn * IN_ + i] : 0.f;
        h[idx] = v;
        h16[idx] = (f16)v;
        if (i < IN_) hin16[bn * IN_ + i] = (f16)v;
    }
    if (idx >= WPACK_SZ) return;
    if (idx < OFF_W2T) {
        int j = idx >> 7, k = idx & 127;
        wp[idx] = (f16)We1[k * 256 + j];
    } else if (idx < OFF_WE3H) {
        int t = idx - OFF_W2T;
        int j = t >> 8, k = t & 255;
        wp[idx] = (f16)We2[k * 128 + j];
    } else if (idx < OFF_RI0) {
        wp[idx] = (f16)We3[idx - OFF_WE3H];
    } else if (idx < OFF_RI1) {
        int t = idx - OFF_RI0;
        int n = t / 96, c = t % 96;
        wp[idx] = (f16)Wi0[c * 128 + n];
    } else if (idx < OFF_RI2) {
        int t = idx - OFF_RI1;
        int n = t >> 7, k = t & 127;
        wp[idx] = (f16)Wi1[k * 256 + n];
    } else if (idx < OFF_RI3) {
        int t = idx - OFF_RI2;
        int n = t >> 8, k = t & 255;
        wp[idx] = (f16)Wi2[k * 128 + n];
    } else if (idx < OFF_RJ0) {
        int t = idx - OFF_RI3;
        int n = t >> 7, k = t & 127;
        wp[idx] = (f16)Wi3[k * 32 + n];
    } else if (idx < OFF_RJ1) {
        int t = idx - OFF_RJ0;
        int n = t >> 6, c = t & 63;
        wp[idx] = (f16)Wj0[c * 128 + n];
    } else if (idx < OFF_RJ2) {
        int t = idx - OFF_RJ1;
        int n = t >> 7, k = t & 127;
        wp[idx] = (f16)Wj1[k * 256 + n];
    } else if (idx < OFF_RJ3) {
        int t = idx - OFF_RJ2;
        int n = t >> 8, k = t & 255;
        wp[idx] = (f16)Wj2[k * 128 + n];
    } else {
        int t = idx - OFF_RJ3;
        int n = t >> 7, k = t & 127;
        wp[idx] = (f16)Wj3[k * 32 + n];
    }
}

// ===================== task bodies ========================================

__device__ void edge_body(SmemU& su, int tid, int tile,
                          const float* __restrict__ am,
                          const float* __restrict__ We0,
                          const float* __restrict__ be0,
                          const f16* __restrict__ W1t,
                          const float* __restrict__ be1,
                          const f16* __restrict__ W2t,
                          const float* __restrict__ be2,
                          f16* __restrict__ f) {
    int lane = tid & 63, wv = tid >> 6;
    long long g0 = (long long)tile * 64;

    ((float*)su.e.xl)[tid] = am[g0 * 4 + tid];
    __syncthreads();

    {   // layer 1: K=4, VALU
        int j = tid & 127, e0 = (tid >> 7) * 32;
        float w0 = We0[j], w1 = We0[128 + j], w2 = We0[256 + j], w3 = We0[384 + j];
        float bb = be0[j];
        #pragma unroll 8
        for (int e = e0; e < e0 + 32; ++e) {
            float v = bb + su.e.xl[e][0] * w0 + su.e.xl[e][1] * w1
                         + su.e.xl[e][2] * w2 + su.e.xl[e][3] * w3;
            su.e.y1[e][j] = (f16)fmaxf(v, 0.f);
        }
    }
    __syncthreads();

    int m = lane & 15, q = lane >> 4;

    {   // layer 2
        f32x4 acc[4][4];
        #pragma unroll
        for (int ct = 0; ct < 4; ++ct)
            #pragma unroll
            for (int rt = 0; rt < 4; ++rt) acc[ct][rt] = (f32x4){0.f, 0.f, 0.f, 0.f};
        #pragma unroll
        for (int s = 0; s < 4; ++s) {
            int k0 = s * 32 + q * 8;
            f16x8 afr[4], bfr[4];
            #pragma unroll
            for (int rt = 0; rt < 4; ++rt)
                afr[rt] = *(const f16x8*)&su.e.y1[rt * 16 + m][k0];
            #pragma unroll
            for (int ct = 0; ct < 4; ++ct) {
                int n = (wv * 4 + ct) * 16 + m;
                bfr[ct] = *(const f16x8*)(W1t + n * 128 + k0);
            }
            #pragma unroll
            for (int ct = 0; ct < 4; ++ct)
                #pragma unroll
                for (int rt = 0; rt < 4; ++rt)
                    acc[ct][rt] = MFMA16(afr[rt], bfr[ct], acc[ct][rt]);
        }
        #pragma unroll
        for (int ct = 0; ct < 4; ++ct) {
            int n = (wv * 4 + ct) * 16 + m;
            float bb = be1[n];
            #pragma unroll
            for (int rt = 0; rt < 4; ++rt)
                #pragma unroll
                for (int r = 0; r < 4; ++r) {
                    int row = rt * 16 + q * 4 + r;
                    su.e.y2[row][n] = (f16)fmaxf(acc[ct][rt][r] + bb, 0.f);
                }
        }
    }
    __syncthreads();

    {   // layer 3 (out-stage back into y1)
        f32x4 acc[2][4];
        #pragma unroll
        for (int ct = 0; ct < 2; ++ct)
            #pragma unroll
            for (int rt = 0; rt < 4; ++rt) acc[ct][rt] = (f32x4){0.f, 0.f, 0.f, 0.f};
        #pragma unroll
        for (int s = 0; s < 8; ++s) {
            int k0 = s * 32 + q * 8;
            f16x8 afr[4], bfr[2];
            #pragma unroll
            for (int rt = 0; rt < 4; ++rt)
                afr[rt] = *(const f16x8*)&su.e.y2[rt * 16 + m][k0];
            #pragma unroll
            for (int ct = 0; ct < 2; ++ct) {
                int n = (wv * 2 + ct) * 16 + m;
                bfr[ct] = *(const f16x8*)(W2t + n * 256 + k0);
            }
            #pragma unroll
            for (int ct = 0; ct < 2; ++ct)
                #pragma unroll
                for (int rt = 0; rt < 4; ++rt)
                    acc[ct][rt] = MFMA16(afr[rt], bfr[ct], acc[ct][rt]);
        }
        #pragma unroll
        for (int ct = 0; ct < 2; ++ct) {
            int n = (wv * 2 + ct) * 16 + m;
            float bb = be2[n];
            #pragma unroll
            for (int rt = 0; rt < 4; ++rt)
                #pragma unroll
                for (int r = 0; r < 4; ++r) {
                    int row = rt * 16 + q * 4 + r;
                    su.e.y1[row][n] = (f16)fmaxf(acc[ct][rt][r] + bb, 0.f);
                }
        }
    }
    __syncthreads();

    #pragma unroll
    for (int j = 0; j < 4; ++j) {
        int c = tid + j * 256;
        int e = c >> 4, pp = c & 15;
        *(uint4*)(f + (g0 + e) * 128 + pp * 8) = *(const uint4*)&su.e.y1[e][pp * 8];
    }
}

// 64-node-row P tile: P2[(b,w),o,k], rows nt*64..+63
__device__ void pgemm_body(SmemU& su, int tid, int ob, int nt,
                           const f16* __restrict__ h16,
                           const f16* __restrict__ We3h,
                           f16* __restrict__ P2) {
    int lane = tid & 63, wv = tid >> 6;

    #pragma unroll
    for (int j = 0; j < 2; ++j) {
        int c = tid + j * 256;        // 0..511 : 64 rows x 8 uint4
        int row = c >> 3, pp = c & 7;
        *(uint4*)&su.pg.Al[row][pp * 8] =
            *(const uint4*)(h16 + (size_t)(nt * 64 + row) * 64 + pp * 8);
    }
    #pragma unroll
    for (int j = 0; j < 4; ++j) {
        int c = tid + j * 256;        // 0..1023 : 128 k-rows x 8 uint4
        int k = c >> 3, pp = c & 7;
        *(uint4*)&su.pg.Bl[k][pp * 8] =
            *(const uint4*)(We3h + ((size_t)(k * 64 + ob)) * 64 + pp * 8);
    }
    __syncthreads();

    int m = lane & 15, q = lane >> 4;
    f32x4 acc[2][4];
    #pragma unroll
    for (int ct = 0; ct < 2; ++ct)
        #pragma unroll
        for (int rt = 0; rt < 4; ++rt) acc[ct][rt] = (f32x4){0.f, 0.f, 0.f, 0.f};
    #pragma unroll
    for (int s = 0; s < 2; ++s) {
        int k0 = s * 32 + q * 8;
        f16x8 afr[4], bfr[2];
        #pragma unroll
        for (int rt = 0; rt < 4; ++rt)
            afr[rt] = *(const f16x8*)&su.pg.Al[rt * 16 + m][k0];
        #pragma unroll
        for (int ct = 0; ct < 2; ++ct)
            bfr[ct] = *(const f16x8*)&su.pg.Bl[(wv * 2 + ct) * 16 + m][k0];
        #pragma unroll
        for (int ct = 0; ct < 2; ++ct)
            #pragma unroll
            for (int rt = 0; rt < 4; ++rt)
                acc[ct][rt] = MFMA16(afr[rt], bfr[ct], acc[ct][rt]);
    }
    #pragma unroll
    for (int ct = 0; ct < 2; ++ct) {
        int col = (wv * 2 + ct) * 16 + m;
        #pragma unroll
        for (int rt = 0; rt < 4; ++rt)
            #pragma unroll
            for (int r = 0; r < 4; ++r)
                su.pg.Ol[rt * 16 + q * 4 + r][col] = (f16)acc[ct][rt][r];
    }
    __syncthreads();
    #pragma unroll
    for (int j = 0; j < 4; ++j) {
        int c = tid + j * 256;        // 0..1023 : 64 rows x 16 uint4
        int row = c >> 4, pp = c & 15;
        *(uint4*)(P2 + ((size_t)(nt * 64 + row) * 64 + ob) * 128 + pp * 8) =
            *(const uint4*)&su.pg.Ol[row][pp * 8];
    }
}

// biasb[b,o] = sum_i be3[o*64+i] * (sum_w h[b,w,i])
__device__ void bias_body(SmemU& su, int tid, int b,
                          const float* __restrict__ h,
                          const float* __restrict__ be3,
                          float* __restrict__ biasb) {
    int i = tid & 63, wq = tid >> 6;
    float s = 0.f;
    for (int w = wq; w < N; w += 4) s += h[((size_t)(b * N + w)) * H + i];
    su.bi.prt[wq][i] = s;
    __syncthreads();
    if (tid < 64)
        su.bi.hsum[tid] = su.bi.prt[0][tid] + su.bi.prt[1][tid]
                        + su.bi.prt[2][tid] + su.bi.prt[3][tid];
    __syncthreads();
    if (tid < 64) {
        float sb = 0.f;
        #pragma unroll 4
        for (int ii = 0; ii < H; ++ii) sb += be3[tid * H + ii] * su.bi.hsum[ii];
        biasb[b * 64 + tid] = sb;
    }
}

// -------------------------------------------------------------------------
// mega0: edge (0..4095) + L0 pgemm64 (4096..6143) + L0 bias (6144..6159)
__global__ __launch_bounds__(256, 3) void mega0_kernel(
    const float* __restrict__ am,
    const float* __restrict__ We0, const float* __restrict__ be0,
    const float* __restrict__ be1, const float* __restrict__ be2,
    const float* __restrict__ be3,
    const f16* __restrict__ wp,
    const float* __restrict__ h, const f16* __restrict__ h16,
    f16* __restrict__ f, f16* __restrict__ P2, float* __restrict__ biasb) {
    __shared__ SmemU su;
    int tid = threadIdx.x;
    int bid = blockIdx.x;
    if (bid < 4096) {
        edge_body(su, tid, bid, am, We0, be0, wp + OFF_W1T, be1, wp + OFF_W2T,
                  be2, f);
    } else if (bid < 6144) {
        int t = bid - 4096;
        pgemm_body(su, tid, t & 63, t >> 6, h16, wp + OFF_WE3H, P2);
    } else {
        bias_body(su, tid, bid - 6144, h, be3, biasb);
    }
}

// pg_bias: pgemm64 (0..2047) + bias (2048..2063), for layers 1,2
__global__ __launch_bounds__(256, 3) void pg_bias_kernel(
    const float* __restrict__ be3, const f16* __restrict__ wp,
    const float* __restrict__ h, const f16* __restrict__ h16,
    f16* __restrict__ P2, float* __restrict__ biasb) {
    __shared__ SmemU su;
    int tid = threadIdx.x;
    int bid = blockIdx.x;
    if (bid < 2048) {
        pgemm_body(su, tid, bid & 63, bid >> 6, h16, wp + OFF_WE3H, P2);
    } else {
        bias_body(su, tid, bid - 2048, h, be3, biasb);
    }
}

// -------------------------------------------------------------------------
// msg GEMM (R9-proven): part[ws][(b,v),o] = sum_{w in split} sum_k f*P2.
// Plain stores, no atomics, no fences.
__global__ __launch_bounds__(256, 2) void msg_mfma(
    const f16* __restrict__ f, const f16* __restrict__ P2,
    float* __restrict__ part) {
    __shared__ f16 Al[128][136];
    __shared__ f16 Bl[64][136];
    int tid = threadIdx.x, lane = tid & 63, wv = tid >> 6;
    int ws = blockIdx.x;
    int b  = blockIdx.y;
    int m = lane & 15, q = lane >> 4;

    f32x4 acc[2][4];
    #pragma unroll
    for (int rt = 0; rt < 2; ++rt)
        #pragma unroll
        for (int ct = 0; ct < 4; ++ct) acc[rt][ct] = (f32x4){0.f, 0.f, 0.f, 0.f};

    for (int wi = 0; wi < 4; ++wi) {
        int w = ws * 4 + wi;
        #pragma unroll
        for (int j = 0; j < 8; ++j) {
            int c = tid + j * 256;
            int v = c >> 4, pp = c & 15;
            *(uint4*)&Al[v][pp * 8] =
                *(const uint4*)(f + (((size_t)(b * 128 + v) * 128 + w) * 128) + pp * 8);
        }
        #pragma unroll
        for (int j = 0; j < 4; ++j) {
            int c = tid + j * 256;
            int o = c >> 4, pp = c & 15;
            *(uint4*)&Bl[o][pp * 8] =
                *(const uint4*)(P2 + (((size_t)(b * 128 + w) * 64 + o) * 128) + pp * 8);
        }
        __syncthreads();
        #pragma unroll
        for (int s = 0; s < 4; ++s) {
            int k0 = s * 32 + q * 8;
            f16x8 afr[2], bfr[4];
            #pragma unroll
            for (int rt = 0; rt < 2; ++rt)
                afr[rt] = *(const f16x8*)&Al[(wv * 2 + rt) * 16 + m][k0];
            #pragma unroll
            for (int ct = 0; ct < 4; ++ct)
                bfr[ct] = *(const f16x8*)&Bl[ct * 16 + m][k0];
            #pragma unroll
            for (int rt = 0; rt < 2; ++rt)
                #pragma unroll
                for (int ct = 0; ct < 4; ++ct)
                    acc[rt][ct] = MFMA16(afr[rt], bfr[ct], acc[rt][ct]);
        }
        __syncthreads();
    }
    float* pp = part + (size_t)ws * (2048 * 64);
    #pragma unroll
    for (int rt = 0; rt < 2; ++rt)
        #pragma unroll
        for (int ct = 0; ct < 4; ++ct) {
            int o = ct * 16 + m;
            #pragma unroll
            for (int r = 0; r < 4; ++r) {
                int v = (wv * 2 + rt) * 16 + q * 4 + r;
                pp[(size_t)(b * 128 + v) * 64 + o] = acc[rt][ct][r];
            }
        }
}

// -------------------------------------------------------------------------
// GRU (R9-proven): msg = biasb[b] + sum of 32 partials; torch GRU; mask.
__global__ __launch_bounds__(192) void gru_kernel(
    const float* __restrict__ biasb, const float* __restrict__ part,
    float* __restrict__ h, f16* __restrict__ h16,
    const float* __restrict__ Wih, const float* __restrict__ Whh,
    const float* __restrict__ bih, const float* __restrict__ bhh,
    const int* __restrict__ g_size) {
    __shared__ float m_lds[M];
    __shared__ float h_lds[H];
    __shared__ float gi[3 * H], gh[3 * H];
    int tid = threadIdx.x;
    int bv  = blockIdx.x;
    int b = bv >> 7, v = bv & 127;

    if (tid < M) {
        float s = biasb[b * 64 + tid];
        #pragma unroll 8
        for (int sp = 0; sp < 32; ++sp)
            s += part[(size_t)sp * (2048 * 64) + bv * 64 + tid];
        m_lds[tid] = s;
    } else if (tid < M + H) {
        h_lds[tid - M] = h[bv * H + (tid - M)];
    }
    __syncthreads();

    {
        float si = bih[tid], sh = bhh[tid];
        const float* wi = Wih + tid * M;
        const float* wh = Whh + tid * H;
        #pragma unroll 4
        for (int k = 0; k < M; ++k) si += wi[k] * m_lds[k];
        #pragma unroll 4
        for (int k = 0; k < H; ++k) sh += wh[k] * h_lds[k];
        gi[tid] = si;
        gh[tid] = sh;
    }
    __syncthreads();
    if (tid < H) {
        float r = 1.f / (1.f + expf(-(gi[tid] + gh[tid])));
        float z = 1.f / (1.f + expf(-(gi[H + tid] + gh[H + tid])));
        float n = tanhf(gi[2 * H + tid] + r * gh[2 * H + tid]);
        float hv = (1.f - z) * n + z * h_lds[tid];
        float maskf = (v < g_size[b]) ? 1.f : 0.f;
        hv *= maskf;
        h[bv * H + tid] = hv;
        h16[bv * H + tid] = (f16)hv;
    }
}

// -------------------------------------------------------------------------
// Readout via MFMA + fused finalize (last-block pattern, R11/R12-proven).
__global__ __launch_bounds__(256, 4) void readout_final(
    const f16* __restrict__ h16, const f16* __restrict__ hin16,
    const int* __restrict__ g_size, const f16* __restrict__ wp,
    const float* __restrict__ bi0, const float* __restrict__ bi1,
    const float* __restrict__ bi2, const float* __restrict__ bi3,
    const float* __restrict__ bj0, const float* __restrict__ bj1,
    const float* __restrict__ bj2, const float* __restrict__ bj3,
    float* __restrict__ contrib, float* __restrict__ out,
    int* __restrict__ done) {
    __shared__ f16 Xl[32][104];
    __shared__ f16 A1[32][136];
    __shared__ f16 A2[32][264];
    __shared__ float Gl[32][36];
    __shared__ float fin[T];
    __shared__ int lastflag;
    const f16* Ri0 = wp + OFF_RI0; const f16* Ri1 = wp + OFF_RI1;
    const f16* Ri2 = wp + OFF_RI2; const f16* Ri3 = wp + OFF_RI3;
    const f16* Rj0 = wp + OFF_RJ0; const f16* Rj1 = wp + OFF_RJ1;
    const f16* Rj2 = wp + OFF_RJ2; const f16* Rj3 = wp + OFF_RJ3;
    int tid = threadIdx.x, lane = tid & 63, wv = tid >> 6;
    int m = lane & 15, q = lane >> 4;
    int r0 = blockIdx.x * 32;

    {
        int row = tid >> 3, pp = tid & 7;
        *(uint4*)&Xl[row][pp * 8] = *(const uint4*)(h16 + (size_t)(r0 + row) * 64 + pp * 8);
        if (tid < 128) {
            int row2 = tid >> 2, p2 = tid & 3;
            *(uint4*)&Xl[row2][64 + p2 * 8] =
                *(const uint4*)(hin16 + (size_t)(r0 + row2) * 32 + p2 * 8);
        }
    }
    __syncthreads();

    // i-chain L0
    {
        f32x4 acc[2][2];
        #pragma unroll
        for (int ct = 0; ct < 2; ++ct)
            #pragma unroll
            for (int rt = 0; rt < 2; ++rt) acc[ct][rt] = (f32x4){0.f, 0.f, 0.f, 0.f};
        #pragma unroll
        for (int s = 0; s < 3; ++s) {
            int k0 = s * 32 + q * 8;
            f16x8 afr[2], bfr[2];
            #pragma unroll
            for (int rt = 0; rt < 2; ++rt) afr[rt] = *(const f16x8*)&Xl[rt * 16 + m][k0];
            #pragma unroll
            for (int ct = 0; ct < 2; ++ct)
                bfr[ct] = *(const f16x8*)(Ri0 + ((wv * 2 + ct) * 16 + m) * 96 + k0);
            #pragma unroll
            for (int ct = 0; ct < 2; ++ct)
                #pragma unroll
                for (int rt = 0; rt < 2; ++rt)
                    acc[ct][rt] = MFMA16(afr[rt], bfr[ct], acc[ct][rt]);
        }
        #pragma unroll
        for (int ct = 0; ct < 2; ++ct) {
            int n = (wv * 2 + ct) * 16 + m;
            float bb = bi0[n];
            #pragma unroll
            for (int rt = 0; rt < 2; ++rt)
                #pragma unroll
                for (int r = 0; r < 4; ++r)
                    A1[rt * 16 + q * 4 + r][n] = (f16)fmaxf(acc[ct][rt][r] + bb, 0.f);
        }
    }
    __syncthreads();

    // i-chain L1
    {
        f32x4 acc[4][2];
        #pragma unroll
        for (int ct = 0; ct < 4; ++ct)
            #pragma unroll
            for (int rt = 0; rt < 2; ++rt) acc[ct][rt] = (f32x4){0.f, 0.f, 0.f, 0.f};
        #pragma unroll
        for (int s = 0; s < 4; ++s) {
            int k0 = s * 32 + q * 8;
            f16x8 afr[2], bfr[4];
            #pragma unroll
            for (int rt = 0; rt < 2; ++rt) afr[rt] = *(const f16x8*)&A1[rt * 16 + m][k0];
            #pragma unroll
            for (int ct = 0; ct < 4; ++ct)
                bfr[ct] = *(const f16x8*)(Ri1 + ((wv * 4 + ct) * 16 + m) * 128 + k0);
            #pragma unroll
            for (int ct = 0; ct < 4; ++ct)
                #pragma unroll
                for (int rt = 0; rt < 2; ++rt)
                    acc[ct][rt] = MFMA16(afr[rt], bfr[ct], acc[ct][rt]);
        }
        #pragma unroll
        for (int ct = 0; ct < 4; ++ct) {
            int n = (wv * 4 + ct) * 16 + m;
            float bb = bi1[n];
            #pragma unroll
            for (int rt = 0; rt < 2; ++rt)
                #pragma unroll
                for (int r = 0; r < 4; ++r)
                    A2[rt * 16 + q * 4 + r][n] = (f16)fmaxf(acc[ct][rt][r] + bb, 0.f);
        }
    }
    __syncthreads();

    // i-chain L2
    {
        f32x4 acc[2][2];
        #pragma unroll
        for (int ct = 0; ct < 2; ++ct)
            #pragma unroll
            for (int rt = 0; rt < 2; ++rt) acc[ct][rt] = (f32x4){0.f, 0.f, 0.f, 0.f};
        #pragma unroll
        for (int s = 0; s < 8; ++s) {
            int k0 = s * 32 + q * 8;
            f16x8 afr[2], bfr[2];
            #pragma unroll
            for (int rt = 0; rt < 2; ++rt) afr[rt] = *(const f16x8*)&A2[rt * 16 + m][k0];
            #pragma unroll
            for (int ct = 0; ct < 2; ++ct)
                bfr[ct] = *(const f16x8*)(Ri2 + ((wv * 2 + ct) * 16 + m) * 256 + k0);
            #pragma unroll
            for (int ct = 0; ct < 2; ++ct)
                #pragma unroll
                for (int rt = 0; rt < 2; ++rt)
                    acc[ct][rt] = MFMA16(afr[rt], bfr[ct], acc[ct][rt]);
        }
        __syncthreads();
        #pragma unroll
        for (int ct = 0; ct < 2; ++ct) {
            int n = (wv * 2 + ct) * 16 + m;
            float bb = bi2[n];
            #pragma unroll
            for (int rt = 0; rt < 2; ++rt)
                #pragma unroll
                for (int r = 0; r < 4; ++r)
                    A1[rt * 16 + q * 4 + r][n] = (f16)fmaxf(acc[ct][rt][r] + bb, 0.f);
        }
    }
    __syncthreads();

    // i-chain L3 -> gate
    if (wv < 2) {
        f32x4 acc[2];
        acc[0] = (f32x4){0.f, 0.f, 0.f, 0.f};
        acc[1] = (f32x4){0.f, 0.f, 0.f, 0.f};
        int n = wv * 16 + m;
        #pragma unroll
        for (int s = 0; s < 4; ++s) {
            int k0 = s * 32 + q * 8;
            f16x8 bfr = *(const f16x8*)(Ri3 + n * 128 + k0);
            #pragma unroll
            for (int rt = 0; rt < 2; ++rt) {
                f16x8 afr = *(const f16x8*)&A1[rt * 16 + m][k0];
                acc[rt] = MFMA16(afr, bfr, acc[rt]);
            }
        }
        float bb = bi3[n];
        #pragma unroll
        for (int rt = 0; rt < 2; ++rt)
            #pragma unroll
            for (int r = 0; r < 4; ++r)
                Gl[rt * 16 + q * 4 + r][n] = 1.f / (1.f + expf(-(acc[rt][r] + bb)));
    }
    __syncthreads();

    // j-chain L0
    {
        f32x4 acc[2][2];
        #pragma unroll
        for (int ct = 0; ct < 2; ++ct)
            #pragma unroll
            for (int rt = 0; rt < 2; ++rt) acc[ct][rt] = (f32x4){0.f, 0.f, 0.f, 0.f};
        #pragma unroll
        for (int s = 0; s < 2; ++s) {
            int k0 = s * 32 + q * 8;
            f16x8 afr[2], bfr[2];
            #pragma unroll
            for (int rt = 0; rt < 2; ++rt) afr[rt] = *(const f16x8*)&Xl[rt * 16 + m][k0];
            #pragma unroll
            for (int ct = 0; ct < 2; ++ct)
                bfr[ct] = *(const f16x8*)(Rj0 + ((wv * 2 + ct) * 16 + m) * 64 + k0);
            #pragma unroll
            for (int ct = 0; ct < 2; ++ct)
                #pragma unroll
                for (int rt = 0; rt < 2; ++rt)
                    acc[ct][rt] = MFMA16(afr[rt], bfr[ct], acc[ct][rt]);
        }
        __syncthreads();
        #pragma unroll
        for (int ct = 0; ct < 2; ++ct) {
            int n = (wv * 2 + ct) * 16 + m;
            float bb = bj0[n];
            #pragma unroll
            for (int rt = 0; rt < 2; ++rt)
                #pragma unroll
                for (int r = 0; r < 4; ++r)
                    A1[rt * 16 + q * 4 + r][n] = (f16)fmaxf(acc[ct][rt][r] + bb, 0.f);
        }
    }
    __syncthreads();

    // j-chain L1
    {
        f32x4 acc[4][2];
        #pragma unroll
        for (int ct = 0; ct < 4; ++ct)
            #pragma unroll
            for (int rt = 0; rt < 2; ++rt) acc[ct][rt] = (f32x4){0.f, 0.f, 0.f, 0.f};
        #pragma unroll
        for (int s = 0; s < 4; ++s) {
            int k0 = s * 32 + q * 8;
            f16x8 afr[2], bfr[4];
            #pragma unroll
            for (int rt = 0; rt < 2; ++rt) afr[rt] = *(const f16x8*)&A1[rt * 16 + m][k0];
            #pragma unroll
            for (int ct = 0; ct < 4; ++ct)
                bfr[ct] = *(const f16x8*)(Rj1 + ((wv * 4 + ct) * 16 + m) * 128 + k0);
            #pragma unroll
            for (int ct = 0; ct < 4; ++ct)
                #pragma unroll
                for (int rt = 0; rt < 2; ++rt)
                    acc[ct][rt] = MFMA16(afr[rt], bfr[ct], acc[ct][rt]);
        }
        #pragma unroll
        for (int ct = 0; ct < 4; ++ct) {
            int n = (wv * 4 + ct) * 16 + m;
            float bb = bj1[n];
            #pragma unroll
            for (int rt = 0; rt < 2; ++rt)
                #pragma unroll
                for (int r = 0; r < 4; ++r)
                    A2[rt * 16 + q * 4 + r][n] = (f16)fmaxf(acc[ct][rt][r] + bb, 0.f);
        }
    }
    __syncthreads();

    // j-chain L2
    {
        f32x4 acc[2][2];
        #pragma unroll
        for (int ct = 0; ct < 2; ++ct)
            #pragma unroll
            for (int rt = 0; rt < 2; ++rt) acc[ct][rt] = (f32x4){0.f, 0.f, 0.f, 0.f};
        #pragma unroll
        for (int s = 0; s < 8; ++s) {
            int k0 = s * 32 + q * 8;
            f16x8 afr[2], bfr[2];
            #pragma unroll
            for (int rt = 0; rt < 2; ++rt) afr[rt] = *(const f16x8*)&A2[rt * 16 + m][k0];
            #pragma unroll
            for (int ct = 0; ct < 2; ++ct)
                bfr[ct] = *(const f16x8*)(Rj2 + ((wv * 2 + ct) * 16 + m) * 256 + k0);
            #pragma unroll
            for (int ct = 0; ct < 2; ++ct)
                #pragma unroll
                for (int rt = 0; rt < 2; ++rt)
                    acc[ct][rt] = MFMA16(afr[rt], bfr[ct], acc[ct][rt]);
        }
        __syncthreads();
        #pragma unroll
        for (int ct = 0; ct < 2; ++ct) {
            int n = (wv * 2 + ct) * 16 + m;
            float bb = bj2[n];
            #pragma unroll
            for (int rt = 0; rt < 2; ++rt)
                #pragma unroll
                for (int r = 0; r < 4; ++r)
                    A1[rt * 16 + q * 4 + r][n] = (f16)fmaxf(acc[ct][rt][r] + bb, 0.f);
        }
    }
    __syncthreads();

    // j-chain L3 + combine
    if (wv < 2) {
        f32x4 acc[2];
        acc[0] = (f32x4){0.f, 0.f, 0.f, 0.f};
        acc[1] = (f32x4){0.f, 0.f, 0.f, 0.f};
        int n = wv * 16 + m;
        #pragma unroll
        for (int s = 0; s < 4; ++s) {
            int k0 = s * 32 + q * 8;
            f16x8 bfr = *(const f16x8*)(Rj3 + n * 128 + k0);
            #pragma unroll
            for (int rt = 0; rt < 2; ++rt) {
                f16x8 afr = *(const f16x8*)&A1[rt * 16 + m][k0];
                acc[rt] = MFMA16(afr, bfr, acc[rt]);
            }
        }
        float bb = bj3[n];
        #pragma unroll
        for (int rt = 0; rt < 2; ++rt)
            #pragma unroll
            for (int r = 0; r < 4; ++r) {
                int row = rt * 16 + q * 4 + r;
                int rg = r0 + row;
                int bb2 = rg >> 7, v = rg & 127;
                float maskf = (v < g_size[bb2]) ? 1.f : 0.f;
                contrib[(size_t)rg * T + n] = maskf * Gl[row][n] * (acc[rt][r] + bb);
            }
    }

    // ---- fused finalize: last arriving block does the 16 log_softmax rows
    __syncthreads();
    __threadfence();
    if (tid == 0) lastflag = (atomicAdd(done, 1) == 63);
    __syncthreads();
    if (!lastflag) return;
    __threadfence();
    for (int b = 0; b < B; ++b) {
        if (tid < T) {
            float s = 0.f;
            for (int v = 0; v < N; ++v) s += contrib[(b * N + v) * T + tid];
            fin[tid] = s;
        }
        __syncthreads();
        if (tid < T) {
            float mx = fin[0];
            for (int i = 1; i < T; ++i) mx = fmaxf(mx, fin[i]);
            float se = 0.f;
            for (int i = 0; i < T; ++i) se += expf(fin[i] - mx);
            out[b * T + tid] = fin[tid] - mx - logf(se);
        }
        __syncthreads();
    }
}

// -------------------------------------------------------------------------
extern "C" void kernel_launch(void* const* d_in, const int* in_sizes, int n_in,
                              void* d_out, int out_size, void* d_ws, size_t ws_size,
                              hipStream_t stream) {
    (void)in_sizes; (void)n_in; (void)out_size; (void)ws_size;
    const float* h_in = (const float*)d_in[0];
    const float* am   = (const float*)d_in[1];
    const int*   g_sz = (const int*)d_in[2];
    const float* We0 = (const float*)d_in[3],  *be0 = (const float*)d_in[4];
    const float* We1 = (const float*)d_in[5],  *be1 = (const float*)d_in[6];
    const float* We2 = (const float*)d_in[7],  *be2 = (const float*)d_in[8];
    const float* We3 = (const float*)d_in[9],  *be3 = (const float*)d_in[10];
    const float* Wih = (const float*)d_in[11], *Whh = (const float*)d_in[12];
    const float* bih = (const float*)d_in[13], *bhh = (const float*)d_in[14];
    const float* Wi0 = (const float*)d_in[15], *bi0 = (const float*)d_in[16];
    const float* Wj0 = (const float*)d_in[17], *bj0 = (const float*)d_in[18];
    const float* Wi1 = (const float*)d_in[19], *bi1 = (const float*)d_in[20];
    const float* Wj1 = (const float*)d_in[21], *bj1 = (const float*)d_in[22];
    const float* Wi2 = (const float*)d_in[23], *bi2 = (const float*)d_in[24];
    const float* Wj2 = (const float*)d_in[25], *bj2 = (const float*)d_in[26];
    const float* Wi3 = (const float*)d_in[27], *bi3 = (const float*)d_in[28];
    const float* Wj3 = (const float*)d_in[29], *bj3 = (const float*)d_in[30];

    float* out = (float*)d_out;

    // workspace layout: done counters first (zeroed by prep, no memset launch)
    int*   done_ro = (int*)d_ws;                           // 64 ints
    f16*   f    = (f16*)((char*)d_ws + 1024);              // 33554432 halves
    f16*   P2   = f + (size_t)33554432;                    // 16777216 halves
    float* part = (float*)(P2 + (size_t)16777216);         // 4194304 floats
    float* h    = part + (size_t)4194304;                  // 131072
    float* biasb = h + 131072;                             // 1024
    float* contrib = biasb + 1024;                         // 65536
    f16*   h16  = (f16*)(contrib + 65536);                 // 131072 halves
    f16*   hin16 = h16 + 131072;                           // 65536 halves
    f16*   wp   = hin16 + 65536;                           // 749568 halves

    prep_kernel<<<(WPACK_SZ + 255) / 256, 256, 0, stream>>>(
        h_in, We1, We2, We3, Wi0, Wi1, Wi2, Wi3, Wj0, Wj1, Wj2, Wj3,
        h, h16, hin16, wp, done_ro);

    // layer 0: edge + pgemm64 + bias in one launch
    mega0_kernel<<<4096 + 2048 + 16, 256, 0, stream>>>(
        am, We0, be0, be1, be2, be3, wp, h, h16, f, P2, biasb);
    msg_mfma<<<dim3(32, 16), 256, 0, stream>>>(f, P2, part);
    gru_kernel<<<B * N, 192, 0, stream>>>(biasb, part, h, h16,
                                          Wih, Whh, bih, bhh, g_sz);

    for (int l = 1; l < 3; ++l) {
        pg_bias_kernel<<<2048 + 16, 256, 0, stream>>>(be3, wp, h, h16, P2, biasb);
        msg_mfma<<<dim3(32, 16), 256, 0, stream>>>(f, P2, part);
        gru_kernel<<<B * N, 192, 0, stream>>>(biasb, part, h, h16,
                                              Wih, Whh, bih, bhh, g_sz);
    }

    readout_final<<<64, 256, 0, stream>>>(h16, hin16, g_sz, wp,
                                          bi0, bi1, bi2, bi3,
                                          bj0, bj1, bj2, bj3, contrib, out,
                                          done_ro);
}